// Round 1
// baseline (6860.621 us; speedup 1.0000x reference)
//
#include <hip/hip_runtime.h>
#include <math.h>

#define SLEN 512
#define BATCH 32
#define IDIM 768
#define HDIM 256
#define NDIM 1024  // 4*HDIM

typedef unsigned short u16;
typedef unsigned int u32;
typedef __attribute__((ext_vector_type(8))) short short8;     // 8 bf16 (MFMA A/B frag)
typedef __attribute__((ext_vector_type(4))) float float4v;    // MFMA C/D frag
typedef __attribute__((ext_vector_type(4))) unsigned short ushort4v;
typedef __attribute__((ext_vector_type(4))) unsigned int uint4v;

__device__ __forceinline__ float bf2f(u16 v) {
    union { u32 u; float f; } c; c.u = ((u32)v) << 16; return c.f;
}
__device__ __forceinline__ u16 f2bf(float f) {
    union { float f; u32 u; } c; c.f = f;
    u32 u = c.u;
    return (u16)((u + 0x7fffu + ((u >> 16) & 1u)) >> 16);
}
__device__ __forceinline__ float sigm(float x) { return 1.f / (1.f + __expf(-x)); }
__device__ __forceinline__ float tanh_f(float x) { return 1.f - 2.f / (__expf(2.f * x) + 1.f); }

struct WPtrs {
    const float *Wi, *Ui, *bi, *Wf, *Uf, *bfp, *Wog, *Uog, *bog, *Wc, *Uc, *bc, *Wd, *bd;
};

// ---------------- kernel 0: weight conversion ----------------
// W4t: bf16 [1024 n][768 k]  (transposed concat of Wi,Wf,Wog,Wc) for GEMM B-frags
// U4 : bf16 [4 g][256 k][256 n]  (natural layout, streamed in recurrence)
// Wdb: bf16 [256 k][256 n]
// b4 : fp32 [1024] concat biases
__global__ void convert_kernel(WPtrs p, u16* __restrict__ W4t, u16* __restrict__ U4,
                               u16* __restrict__ Wdb, float* __restrict__ b4) {
    const float* Wg[4] = {p.Wi, p.Wf, p.Wog, p.Wc};
    const float* Ug[4] = {p.Ui, p.Uf, p.Uog, p.Uc};
    const float* bg[4] = {p.bi, p.bfp, p.bog, p.bc};
    const int total = NDIM * IDIM + 4 * HDIM * HDIM + HDIM * HDIM + NDIM;
    for (int idx = blockIdx.x * blockDim.x + threadIdx.x; idx < total;
         idx += gridDim.x * blockDim.x) {
        int i = idx;
        if (i < NDIM * IDIM) {
            int n = i / IDIM, k = i - n * IDIM;
            W4t[i] = f2bf(Wg[n >> 8][k * HDIM + (n & 255)]);
        } else if ((i -= NDIM * IDIM) < 4 * HDIM * HDIM) {
            U4[i] = f2bf(Ug[i >> 16][i & 65535]);
        } else if ((i -= 4 * HDIM * HDIM) < HDIM * HDIM) {
            Wdb[i] = f2bf(p.Wd[i]);
        } else {
            i -= HDIM * HDIM;
            b4[i] = bg[i >> 8][i & 255];
        }
    }
}

// ---------------- kernel 1: G = x @ W4 + b4  (bf16 MFMA, 128x128 tiles) ----------------
// x: fp32 (16384 x 768) row-major.  W4t: bf16 (1024 x 768) = B^T.  G: bf16 (16384 x 1024).
__global__ __launch_bounds__(256) void gemm_g_kernel(const float* __restrict__ x,
                                                     const u16* __restrict__ W4t,
                                                     const float* __restrict__ b4,
                                                     u16* __restrict__ G) {
    // row stride 40 u16 = 80 B (odd multiple of 16 B: aligned b128 + bank-spread)
    __shared__ u16 As[128][40];
    __shared__ u16 Bs[128][40];
    const int bn = blockIdx.x;   // 0..7   (N tiles)
    const int bm = blockIdx.y;   // 0..127 (M tiles)
    const int tid = threadIdx.x;
    const int w = tid >> 6, lane = tid & 63;
    const int wr = w >> 1, wc = w & 1;
    const int l15 = lane & 15, quad = lane >> 4;
    const int m0 = bm * 128, n0 = bn * 128;

    float4v acc[4][4];
#pragma unroll
    for (int a = 0; a < 4; ++a)
#pragma unroll
        for (int b = 0; b < 4; ++b) acc[a][b] = (float4v)(0.f);

    for (int kt = 0; kt < IDIM / 32; ++kt) {
        const int k0 = kt * 32;
        // stage A: 128 rows x 32 k, fp32 -> bf16
#pragma unroll
        for (int i = 0; i < 4; ++i) {
            int idx = tid + 256 * i;           // 0..1023
            int r = idx >> 3, seg = idx & 7;   // seg = which float4 within 32 floats
            float4v xv = *(const float4v*)(x + (size_t)(m0 + r) * IDIM + k0 + seg * 4);
            ushort4v t;
            t.x = f2bf(xv.x); t.y = f2bf(xv.y); t.z = f2bf(xv.z); t.w = f2bf(xv.w);
            *(ushort4v*)(&As[r][seg * 4]) = t;
        }
        // stage B: 128 n-rows x 32 k, bf16 direct (16B chunks)
#pragma unroll
        for (int i = 0; i < 2; ++i) {
            int idx = tid + 256 * i;           // 0..511
            int r = idx >> 2, seg = idx & 3;   // seg = which 8-elem chunk
            uint4v bv = *(const uint4v*)(W4t + (size_t)(n0 + r) * IDIM + k0 + seg * 8);
            *(uint4v*)(&Bs[r][seg * 8]) = bv;
        }
        __syncthreads();
        short8 afr[4], bfr[4];
#pragma unroll
        for (int mt = 0; mt < 4; ++mt) {
            int row = wr * 64 + mt * 16 + l15;
            afr[mt] = *(const short8*)(&As[row][quad * 8]);
        }
#pragma unroll
        for (int nt = 0; nt < 4; ++nt) {
            int col = wc * 64 + nt * 16 + l15;
            bfr[nt] = *(const short8*)(&Bs[col][quad * 8]);
        }
#pragma unroll
        for (int mt = 0; mt < 4; ++mt)
#pragma unroll
            for (int nt = 0; nt < 4; ++nt)
                acc[mt][nt] = __builtin_amdgcn_mfma_f32_16x16x32_bf16(afr[mt], bfr[nt],
                                                                      acc[mt][nt], 0, 0, 0);
        __syncthreads();
    }
    // epilogue: C layout col=lane&15, row=quad*4+reg (m89-verified)
#pragma unroll
    for (int mt = 0; mt < 4; ++mt)
#pragma unroll
        for (int nt = 0; nt < 4; ++nt) {
            int gm = m0 + wr * 64 + mt * 16 + quad * 4;
            int gn = n0 + wc * 64 + nt * 16 + l15;
            float bias = b4[gn];
#pragma unroll
            for (int r = 0; r < 4; ++r) {
                G[(size_t)(gm + r) * NDIM + gn] = f2bf(acc[mt][nt][r] + bias);
            }
        }
}

// ---------------- kernel 2: recurrence ----------------
// 64 blocks = (dir 2) x (batch 32), 256 threads (thread n owns output column n).
// h,c fp32 in LDS; U streamed bf16 from L2 each step.
__global__ __launch_bounds__(256) void recur_kernel(const float* __restrict__ times,
                                                    const float* __restrict__ bd,
                                                    const u16* __restrict__ U4,
                                                    const u16* __restrict__ Wdb,
                                                    const u16* __restrict__ G,
                                                    float* __restrict__ out) {
    __shared__ float hsh[HDIM];
    __shared__ float csh[HDIM];
    const int d = blockIdx.x >> 5;
    const int b = blockIdx.x & 31;
    const int n = threadIdx.x;
    hsh[n] = 0.f;
    csh[n] = 0.f;
    __syncthreads();
    const float bdec = bd[n];
    const u16* Ui_ = U4 + 0 * 65536 + n;
    const u16* Uf_ = U4 + 1 * 65536 + n;
    const u16* Uo_ = U4 + 2 * 65536 + n;
    const u16* Uc_ = U4 + 3 * 65536 + n;
    const u16* Wd_ = Wdb + n;
    float hn = 0.f, cn = 0.f;

    for (int s = 0; s < SLEN; ++s) {
        const int sf = d ? (SLEN - 1 - s) : s;                 // x/G source row
        const int tt = d ? (s == 0 ? 0 : SLEN - s) : s;        // tb = [t0, t511..t1]
        const float ti = times[b * SLEN + tt];
        const float T = 1.0f / logf(ti + 2.718281828459045f);

        float ai = 0.f, af = 0.f, ao = 0.f, ac = 0.f, ad = 0.f;
#pragma unroll 8
        for (int k = 0; k < HDIM; ++k) {
            float hk = hsh[k], ck = csh[k];
            ai = fmaf(hk, bf2f(Ui_[k * HDIM]), ai);
            af = fmaf(hk, bf2f(Uf_[k * HDIM]), af);
            ao = fmaf(hk, bf2f(Uo_[k * HDIM]), ao);
            ac = fmaf(hk, bf2f(Uc_[k * HDIM]), ac);
            ad = fmaf(ck, bf2f(Wd_[k * HDIM]), ad);
        }
        const u16* Gm = G + (size_t)(b * SLEN + sf) * NDIM;
        const float c_st = tanh_f(ad + bdec);
        const float cs = cn - c_st + T * c_st;   // time-decomposed prev cell
        const float ig = sigm(ai + bf2f(Gm[n]));
        const float fg = sigm(af + bf2f(Gm[HDIM + n]));
        const float og = sigm(ao + bf2f(Gm[2 * HDIM + n]));
        const float Cc = sigm(ac + bf2f(Gm[3 * HDIM + n]));
        cn = fg * cs + ig * Cc;
        hn = og * tanh_f(cn);
        out[((size_t)b * SLEN + s) * 512 + d * HDIM + n] = hn;
        __syncthreads();
        hsh[n] = hn;
        csh[n] = cn;
        __syncthreads();
    }
    // h_last, c_last
    out[(size_t)BATCH * SLEN * 512 + b * 512 + d * HDIM + n] = hn;
    out[(size_t)BATCH * SLEN * 512 + BATCH * 512 + b * 512 + d * HDIM + n] = cn;
}

extern "C" void kernel_launch(void* const* d_in, const int* in_sizes, int n_in,
                              void* d_out, int out_size, void* d_ws, size_t ws_size,
                              hipStream_t stream) {
    const float* inputs = (const float*)d_in[0];
    const float* times = (const float*)d_in[1];
    WPtrs p;
    p.Wi = (const float*)d_in[2];  p.Ui = (const float*)d_in[3];  p.bi = (const float*)d_in[4];
    p.Wf = (const float*)d_in[5];  p.Uf = (const float*)d_in[6];  p.bfp = (const float*)d_in[7];
    p.Wog = (const float*)d_in[8]; p.Uog = (const float*)d_in[9]; p.bog = (const float*)d_in[10];
    p.Wc = (const float*)d_in[11]; p.Uc = (const float*)d_in[12]; p.bc = (const float*)d_in[13];
    p.Wd = (const float*)d_in[14]; p.bd = (const float*)d_in[15];

    char* ws = (char*)d_ws;
    u16* W4t = (u16*)ws;                       // 1024*768*2        = 1,572,864 B
    u16* U4 = (u16*)(ws + 1572864);            // 4*256*256*2       =   524,288 B
    u16* Wdb = (u16*)(ws + 2097152);           // 256*256*2         =   131,072 B
    float* b4 = (float*)(ws + 2228224);        // 1024*4            =     4,096 B
    u16* G = (u16*)(ws + 2232320);             // 16384*1024*2      = 33,554,432 B
    // total ws used: ~35.8 MB

    hipLaunchKernelGGL(convert_kernel, dim3(1024), dim3(256), 0, stream, p, W4t, U4, Wdb, b4);
    hipLaunchKernelGGL(gemm_g_kernel, dim3(8, 128), dim3(256), 0, stream, inputs, W4t, b4, G);
    hipLaunchKernelGGL(recur_kernel, dim3(64), dim3(256), 0, stream, times, p.bd, U4, Wdb, G,
                       (float*)d_out);
}

// Round 2
// 4265.788 us; speedup vs baseline: 1.6083x; 1.6083x over previous
//
#include <hip/hip_runtime.h>
#include <math.h>

#define SLEN 512
#define BATCH 32
#define IDIM 768
#define HDIM 256
#define NDIM 1024  // 4*HDIM

typedef unsigned short u16;
typedef unsigned int u32;
typedef __attribute__((ext_vector_type(8))) short short8;     // 8 bf16 (MFMA A/B frag)
typedef __attribute__((ext_vector_type(4))) float float4v;    // MFMA C/D frag
typedef __attribute__((ext_vector_type(4))) unsigned short ushort4v;
typedef __attribute__((ext_vector_type(4))) unsigned int uint4v;

__device__ __forceinline__ float bf2f(u16 v) {
    union { u32 u; float f; } c; c.u = ((u32)v) << 16; return c.f;
}
__device__ __forceinline__ u16 f2bf(float f) {
    union { float f; u32 u; } c; c.f = f;
    u32 u = c.u;
    return (u16)((u + 0x7fffu + ((u >> 16) & 1u)) >> 16);
}
__device__ __forceinline__ float sigm(float x) { return 1.f / (1.f + __expf(-x)); }
__device__ __forceinline__ float tanh_f(float x) { return 1.f - 2.f / (__expf(2.f * x) + 1.f); }

struct WPtrs {
    const float *Wi, *Ui, *bi, *Wf, *Uf, *bfp, *Wog, *Uog, *bog, *Wc, *Uc, *bc, *Wd, *bd;
};

// ---------------- kernel 0: weight conversion ----------------
// W4t: bf16 [1024 n][768 k]  (transposed concat Wi,Wf,Wog,Wc) for GEMM B-frags
// U4t: bf16 [5 mat][256 n][256 k]  (transposed: i,f,o,c,Wd) for recurrence B-frags
// b4 : fp32 [1024] concat gate biases
__global__ void convert_kernel(WPtrs p, u16* __restrict__ W4t, u16* __restrict__ U4t,
                               float* __restrict__ b4) {
    const float* Wg[4] = {p.Wi, p.Wf, p.Wog, p.Wc};
    const float* Ug[4] = {p.Ui, p.Uf, p.Uog, p.Uc};
    const float* bg[4] = {p.bi, p.bfp, p.bog, p.bc};
    const int total = NDIM * IDIM + 5 * HDIM * HDIM + NDIM;
    for (int idx = blockIdx.x * blockDim.x + threadIdx.x; idx < total;
         idx += gridDim.x * blockDim.x) {
        int i = idx;
        if (i < NDIM * IDIM) {
            int n = i / IDIM, k = i - n * IDIM;
            W4t[i] = f2bf(Wg[n >> 8][k * HDIM + (n & 255)]);
        } else if ((i -= NDIM * IDIM) < 5 * HDIM * HDIM) {
            int g = i >> 16, rem = i & 65535, n = rem >> 8, k = rem & 255;
            const float* M = (g < 4) ? Ug[g] : p.Wd;
            U4t[i] = f2bf(M[k * HDIM + n]);
        } else {
            i -= 5 * HDIM * HDIM;
            b4[i] = bg[i >> 8][i & 255];
        }
    }
}

// ---------------- kernel 1: G = x @ W4 + b4  (bf16 MFMA, 128x128 tiles) ----------------
__global__ __launch_bounds__(256) void gemm_g_kernel(const float* __restrict__ x,
                                                     const u16* __restrict__ W4t,
                                                     const float* __restrict__ b4,
                                                     u16* __restrict__ G) {
    __shared__ u16 As[128][40];
    __shared__ u16 Bs[128][40];
    const int bn = blockIdx.x;   // 0..7
    const int bm = blockIdx.y;   // 0..127
    const int tid = threadIdx.x;
    const int w = tid >> 6, lane = tid & 63;
    const int wr = w >> 1, wc = w & 1;
    const int l15 = lane & 15, quad = lane >> 4;
    const int m0 = bm * 128, n0 = bn * 128;

    float4v acc[4][4];
#pragma unroll
    for (int a = 0; a < 4; ++a)
#pragma unroll
        for (int b = 0; b < 4; ++b) acc[a][b] = (float4v)(0.f);

    for (int kt = 0; kt < IDIM / 32; ++kt) {
        const int k0 = kt * 32;
#pragma unroll
        for (int i = 0; i < 4; ++i) {
            int idx = tid + 256 * i;
            int r = idx >> 3, seg = idx & 7;
            float4v xv = *(const float4v*)(x + (size_t)(m0 + r) * IDIM + k0 + seg * 4);
            ushort4v t;
            t.x = f2bf(xv.x); t.y = f2bf(xv.y); t.z = f2bf(xv.z); t.w = f2bf(xv.w);
            *(ushort4v*)(&As[r][seg * 4]) = t;
        }
#pragma unroll
        for (int i = 0; i < 2; ++i) {
            int idx = tid + 256 * i;
            int r = idx >> 2, seg = idx & 3;
            uint4v bv = *(const uint4v*)(W4t + (size_t)(n0 + r) * IDIM + k0 + seg * 8);
            *(uint4v*)(&Bs[r][seg * 8]) = bv;
        }
        __syncthreads();
        short8 afr[4], bfr[4];
#pragma unroll
        for (int mt = 0; mt < 4; ++mt) {
            int row = wr * 64 + mt * 16 + l15;
            afr[mt] = *(const short8*)(&As[row][quad * 8]);
        }
#pragma unroll
        for (int nt = 0; nt < 4; ++nt) {
            int col = wc * 64 + nt * 16 + l15;
            bfr[nt] = *(const short8*)(&Bs[col][quad * 8]);
        }
#pragma unroll
        for (int mt = 0; mt < 4; ++mt)
#pragma unroll
            for (int nt = 0; nt < 4; ++nt)
                acc[mt][nt] = __builtin_amdgcn_mfma_f32_16x16x32_bf16(afr[mt], bfr[nt],
                                                                      acc[mt][nt], 0, 0, 0);
        __syncthreads();
    }
#pragma unroll
    for (int mt = 0; mt < 4; ++mt)
#pragma unroll
        for (int nt = 0; nt < 4; ++nt) {
            int gm = m0 + wr * 64 + mt * 16 + quad * 4;
            int gn = n0 + wc * 64 + nt * 16 + l15;
            float bias = b4[gn];
#pragma unroll
            for (int r = 0; r < 4; ++r) {
                G[(size_t)(gm + r) * NDIM + gn] = f2bf(acc[mt][nt][r] + bias);
            }
        }
}

// ---------------- kernel 2: recurrence (MFMA, U register-resident, 8-block sync) ----
// 8 blocks = 2 dirs x 4 hidden-slices(64). 256 threads = 4 waves; wave w owns hidden
// cols [slice*64+w*16, +16) for all 5 matrices; B-frags live in VGPRs for all 512 steps.
// h/c exchanged cross-block via double-buffered bf16 global buffers + counter barrier.
__global__ __launch_bounds__(256, 1) void recur_mfma_kernel(
    const float* __restrict__ times, const float* __restrict__ bd,
    const u16* __restrict__ U4t, const u16* __restrict__ G,
    u16* __restrict__ hx, u16* __restrict__ cx, int* __restrict__ cnt,
    float* __restrict__ out) {
    const int d = blockIdx.x >> 2;
    const int slice = blockIdx.x & 3;
    const int tid = threadIdx.x;
    const int w = tid >> 6;
    const int lane = tid & 63;
    const int l15 = lane & 15;
    const int quad = lane >> 4;
    const int j = slice * 64 + w * 16 + l15;  // owned hidden column (C-layout col)
    const float bdec = bd[j];
    const int cidx0 = d * SLEN;

    // B fragments: B[k][n], lane n=l15, k = q*32 + quad*8 + e  -> U4t[mat][n][k] contiguous
    short8 Bf[5][8];
#pragma unroll
    for (int g = 0; g < 5; ++g)
#pragma unroll
        for (int q = 0; q < 8; ++q)
            Bf[g][q] = *(const short8*)(U4t + (g << 16) + (j << 8) + (q << 5) + (quad << 3));

    float creg[2][4], hreg[2][4];
#pragma unroll
    for (int mt = 0; mt < 2; ++mt)
#pragma unroll
        for (int r = 0; r < 4; ++r) { creg[mt][r] = 0.f; hreg[mt][r] = 0.f; }

    for (int s = 0; s < SLEN; ++s) {
        const int sf = d ? (SLEN - 1 - s) : s;              // G source row
        const int tt = d ? (s == 0 ? 0 : SLEN - s) : s;     // tb = [t0, t511..t1]

        // ---- prefetch (independent of barrier): gate preacts from G -> acc init, T ----
        float4v acc[5][2];
#pragma unroll
        for (int g = 0; g < 4; ++g)
#pragma unroll
            for (int mt = 0; mt < 2; ++mt) {
                const u16* Gp = G + (size_t)((mt * 16 + quad * 4) * SLEN + sf) * NDIM + g * 256 + j;
                float4v a;
#pragma unroll
                for (int r = 0; r < 4; ++r) a[r] = bf2f(Gp[(size_t)r * SLEN * NDIM]);
                acc[g][mt] = a;
            }
        float Tv[2][4];
#pragma unroll
        for (int mt = 0; mt < 2; ++mt)
#pragma unroll
            for (int r = 0; r < 4; ++r) {
                const int b = mt * 16 + quad * 4 + r;
                Tv[mt][r] = 1.f / logf(times[b * SLEN + tt] + 2.718281828459045f);
            }
#pragma unroll
        for (int mt = 0; mt < 2; ++mt) acc[4][mt] = (float4v)(bdec);

        // ---- wait for step s-1 h/c from the other 3 blocks of this dir ----
        if (s > 0) {
            if (tid == 0) {
                while (atomicAdd(cnt + cidx0 + s - 1, 0) < 4) {}
            }
            __syncthreads();
            __threadfence();  // acquire: invalidate caches before reading peers' h/c
        }

        // ---- A fragments: A[m][k], lane m=l15, k = q*32 + quad*8 + e ----
        const int pr = (s + 1) & 1;  // s=0 reads parity 1 (pre-zeroed)
        const u16* hb = hx + ((d * 2 + pr) * 32) * 256;
        const u16* cb = cx + ((d * 2 + pr) * 32) * 256;
        short8 Ah[2][8], Ac[2][8];
#pragma unroll
        for (int mt = 0; mt < 2; ++mt)
#pragma unroll
            for (int q = 0; q < 8; ++q) {
                const int off = (mt * 16 + l15) * 256 + q * 32 + quad * 8;
                Ah[mt][q] = *(const short8*)(hb + off);
                Ac[mt][q] = *(const short8*)(cb + off);
            }

#pragma unroll
        for (int q = 0; q < 8; ++q)
#pragma unroll
            for (int mt = 0; mt < 2; ++mt) {
                acc[0][mt] = __builtin_amdgcn_mfma_f32_16x16x32_bf16(Ah[mt][q], Bf[0][q], acc[0][mt], 0, 0, 0);
                acc[1][mt] = __builtin_amdgcn_mfma_f32_16x16x32_bf16(Ah[mt][q], Bf[1][q], acc[1][mt], 0, 0, 0);
                acc[2][mt] = __builtin_amdgcn_mfma_f32_16x16x32_bf16(Ah[mt][q], Bf[2][q], acc[2][mt], 0, 0, 0);
                acc[3][mt] = __builtin_amdgcn_mfma_f32_16x16x32_bf16(Ah[mt][q], Bf[3][q], acc[3][mt], 0, 0, 0);
                acc[4][mt] = __builtin_amdgcn_mfma_f32_16x16x32_bf16(Ac[mt][q], Bf[4][q], acc[4][mt], 0, 0, 0);
            }

        // ---- epilogue: C layout col=l15 (j), row=quad*4+r (batch) ----
        const int pw = s & 1;
        u16* hw = hx + ((d * 2 + pw) * 32) * 256;
        u16* cw = cx + ((d * 2 + pw) * 32) * 256;
#pragma unroll
        for (int mt = 0; mt < 2; ++mt)
#pragma unroll
            for (int r = 0; r < 4; ++r) {
                const int b = mt * 16 + quad * 4 + r;
                const float C_ST = tanh_f(acc[4][mt][r]);
                const float cs = creg[mt][r] - C_ST + Tv[mt][r] * C_ST;
                const float ig = sigm(acc[0][mt][r]);
                const float fg = sigm(acc[1][mt][r]);
                const float og = sigm(acc[2][mt][r]);
                const float Cc = sigm(acc[3][mt][r]);
                const float cn = fg * cs + ig * Cc;
                const float hn = og * tanh_f(cn);
                creg[mt][r] = cn;
                hreg[mt][r] = hn;
                hw[b * 256 + j] = f2bf(hn);
                cw[b * 256 + j] = f2bf(cn);
                out[((size_t)b * SLEN + s) * 512 + d * 256 + j] = hn;
            }
        __threadfence();  // release: flush h/c stores device-wide
        __syncthreads();
        if (tid == 0) atomicAdd(cnt + cidx0 + s, 1);
    }

    // h_last, c_last
    const size_t base2 = (size_t)BATCH * SLEN * 512;
#pragma unroll
    for (int mt = 0; mt < 2; ++mt)
#pragma unroll
        for (int r = 0; r < 4; ++r) {
            const int b = mt * 16 + quad * 4 + r;
            out[base2 + b * 512 + d * 256 + j] = hreg[mt][r];
            out[base2 + BATCH * 512 + b * 512 + d * 256 + j] = creg[mt][r];
        }
}

extern "C" void kernel_launch(void* const* d_in, const int* in_sizes, int n_in,
                              void* d_out, int out_size, void* d_ws, size_t ws_size,
                              hipStream_t stream) {
    const float* inputs = (const float*)d_in[0];
    const float* times = (const float*)d_in[1];
    WPtrs p;
    p.Wi = (const float*)d_in[2];  p.Ui = (const float*)d_in[3];  p.bi = (const float*)d_in[4];
    p.Wf = (const float*)d_in[5];  p.Uf = (const float*)d_in[6];  p.bfp = (const float*)d_in[7];
    p.Wog = (const float*)d_in[8]; p.Uog = (const float*)d_in[9]; p.bog = (const float*)d_in[10];
    p.Wc = (const float*)d_in[11]; p.Uc = (const float*)d_in[12]; p.bc = (const float*)d_in[13];
    p.Wd = (const float*)d_in[14]; p.bd = (const float*)d_in[15];

    char* ws = (char*)d_ws;
    u16* W4t = (u16*)ws;                   // 1024*768*2   = 1,572,864 B (GEMM-phase only)
    u16* U4t = (u16*)(ws + 1572864);       // 5*256*256*2  =   655,360 B
    float* b4 = (float*)(ws + 2228224);    // 1024*4       =     4,096 B
    u16* G = (u16*)(ws + 2232320);         // 16384*1024*2 = 33,554,432 B
    // recur-phase aliases into the (dead) W4t region:
    u16* hx = (u16*)ws;                    // [2d][2par][32b][256k] bf16 = 65,536 B
    u16* cx = (u16*)(ws + 65536);          // 65,536 B
    int* cnt = (int*)(ws + 131072);        // [2][512] int = 4,096 B
    // total ws used: 35,786,752 B (same as round 1)

    hipLaunchKernelGGL(convert_kernel, dim3(1024), dim3(256), 0, stream, p, W4t, U4t, b4);
    hipLaunchKernelGGL(gemm_g_kernel, dim3(8, 128), dim3(256), 0, stream, inputs, W4t, b4, G);
    hipMemsetAsync(ws, 0, 135168, stream);  // zero hx, cx, cnt (after gemm is done with W4t)
    hipLaunchKernelGGL(recur_mfma_kernel, dim3(8), dim3(256), 0, stream, times, p.bd, U4t, G,
                       hx, cx, cnt, (float*)d_out);
}

// Round 3
// 3125.514 us; speedup vs baseline: 2.1950x; 1.3648x over previous
//
#include <hip/hip_runtime.h>
#include <math.h>

#define SLEN 512
#define BATCH 32
#define IDIM 768
#define HDIM 256
#define NDIM 1024  // 4*HDIM

typedef unsigned short u16;
typedef unsigned int u32;
typedef unsigned long long u64;
typedef __attribute__((ext_vector_type(8))) short short8;     // 8 bf16 (MFMA A/B frag)
typedef __attribute__((ext_vector_type(4))) float float4v;    // MFMA C/D frag
typedef __attribute__((ext_vector_type(4))) unsigned short ushort4v;
typedef __attribute__((ext_vector_type(4))) unsigned int uint4v;

__device__ __forceinline__ float bf2f(u16 v) {
    union { u32 u; float f; } c; c.u = ((u32)v) << 16; return c.f;
}
__device__ __forceinline__ u16 f2bf(float f) {
    union { float f; u32 u; } c; c.f = f;
    u32 u = c.u;
    return (u16)((u + 0x7fffu + ((u >> 16) & 1u)) >> 16);
}
__device__ __forceinline__ float sigm(float x) { return 1.f / (1.f + __expf(-x)); }
__device__ __forceinline__ float tanh_f(float x) { return 1.f - 2.f / (__expf(2.f * x) + 1.f); }

struct WPtrs {
    const float *Wi, *Ui, *bi, *Wf, *Uf, *bfp, *Wog, *Uog, *bog, *Wc, *Uc, *bc, *Wd, *bd;
};

// ---------------- kernel 0: weight conversion ----------------
// W4t: bf16 [1024 n][768 k]  (transposed concat Wi,Wf,Wog,Wc) for GEMM B-frags
// U4t: bf16 [5 mat][256 n][256 k]  (transposed: i,f,o,c,Wd) for recurrence B-frags
// b4 : fp32 [1024] concat gate biases
__global__ void convert_kernel(WPtrs p, u16* __restrict__ W4t, u16* __restrict__ U4t,
                               float* __restrict__ b4) {
    const float* Wg[4] = {p.Wi, p.Wf, p.Wog, p.Wc};
    const float* Ug[4] = {p.Ui, p.Uf, p.Uog, p.Uc};
    const float* bg[4] = {p.bi, p.bfp, p.bog, p.bc};
    const int total = NDIM * IDIM + 5 * HDIM * HDIM + NDIM;
    for (int idx = blockIdx.x * blockDim.x + threadIdx.x; idx < total;
         idx += gridDim.x * blockDim.x) {
        int i = idx;
        if (i < NDIM * IDIM) {
            int n = i / IDIM, k = i - n * IDIM;
            W4t[i] = f2bf(Wg[n >> 8][k * HDIM + (n & 255)]);
        } else if ((i -= NDIM * IDIM) < 5 * HDIM * HDIM) {
            int g = i >> 16, rem = i & 65535, n = rem >> 8, k = rem & 255;
            const float* M = (g < 4) ? Ug[g] : p.Wd;
            U4t[i] = f2bf(M[k * HDIM + n]);
        } else {
            i -= 5 * HDIM * HDIM;
            b4[i] = bg[i >> 8][i & 255];
        }
    }
}

// ---------------- kernel 1: G = x @ W4 + b4  (bf16 MFMA, 128x128 tiles) ----------------
__global__ __launch_bounds__(256) void gemm_g_kernel(const float* __restrict__ x,
                                                     const u16* __restrict__ W4t,
                                                     const float* __restrict__ b4,
                                                     u16* __restrict__ G) {
    __shared__ u16 As[128][40];
    __shared__ u16 Bs[128][40];
    const int bn = blockIdx.x;   // 0..7
    const int bm = blockIdx.y;   // 0..127
    const int tid = threadIdx.x;
    const int w = tid >> 6, lane = tid & 63;
    const int wr = w >> 1, wc = w & 1;
    const int l15 = lane & 15, quad = lane >> 4;
    const int m0 = bm * 128, n0 = bn * 128;

    float4v acc[4][4];
#pragma unroll
    for (int a = 0; a < 4; ++a)
#pragma unroll
        for (int b = 0; b < 4; ++b) acc[a][b] = (float4v)(0.f);

    for (int kt = 0; kt < IDIM / 32; ++kt) {
        const int k0 = kt * 32;
#pragma unroll
        for (int i = 0; i < 4; ++i) {
            int idx = tid + 256 * i;
            int r = idx >> 3, seg = idx & 7;
            float4v xv = *(const float4v*)(x + (size_t)(m0 + r) * IDIM + k0 + seg * 4);
            ushort4v t;
            t.x = f2bf(xv.x); t.y = f2bf(xv.y); t.z = f2bf(xv.z); t.w = f2bf(xv.w);
            *(ushort4v*)(&As[r][seg * 4]) = t;
        }
#pragma unroll
        for (int i = 0; i < 2; ++i) {
            int idx = tid + 256 * i;
            int r = idx >> 2, seg = idx & 3;
            uint4v bv = *(const uint4v*)(W4t + (size_t)(n0 + r) * IDIM + k0 + seg * 8);
            *(uint4v*)(&Bs[r][seg * 8]) = bv;
        }
        __syncthreads();
        short8 afr[4], bfr[4];
#pragma unroll
        for (int mt = 0; mt < 4; ++mt) {
            int row = wr * 64 + mt * 16 + l15;
            afr[mt] = *(const short8*)(&As[row][quad * 8]);
        }
#pragma unroll
        for (int nt = 0; nt < 4; ++nt) {
            int col = wc * 64 + nt * 16 + l15;
            bfr[nt] = *(const short8*)(&Bs[col][quad * 8]);
        }
#pragma unroll
        for (int mt = 0; mt < 4; ++mt)
#pragma unroll
            for (int nt = 0; nt < 4; ++nt)
                acc[mt][nt] = __builtin_amdgcn_mfma_f32_16x16x32_bf16(afr[mt], bfr[nt],
                                                                      acc[mt][nt], 0, 0, 0);
        __syncthreads();
    }
#pragma unroll
    for (int mt = 0; mt < 4; ++mt)
#pragma unroll
        for (int nt = 0; nt < 4; ++nt) {
            int gm = m0 + wr * 64 + mt * 16 + quad * 4;
            int gn = n0 + wc * 64 + nt * 16 + l15;
            float bias = b4[gn];
#pragma unroll
            for (int r = 0; r < 4; ++r) {
                G[(size_t)(gm + r) * NDIM + gn] = f2bf(acc[mt][nt][r] + bias);
            }
        }
}

// ---------------- kernel 2: recurrence (MFMA, fence-free tagged exchange) ----------
// 8 blocks = 2 dirs x 4 hidden-slices(64). 256 threads = 4 waves; wave w owns hidden
// cols [slice*64+w*16, +16) for all 5 matrices; B-frags in VGPRs for all 512 steps.
// h/c exchanged via double-buffered u64 entries {tag | c | h} with relaxed
// device-scope atomics: tag travels with payload -> no fences, no counters.
__global__ __launch_bounds__(256, 1) void recur_mfma_kernel(
    const float* __restrict__ times, const float* __restrict__ bd,
    const u16* __restrict__ U4t, const u16* __restrict__ G,
    u64* __restrict__ exch, float* __restrict__ out) {
    __shared__ u16 hL[32 * 264];  // [b][k], pad 264
    __shared__ u16 cL[32 * 264];
    const int d = blockIdx.x >> 2;
    const int slice = blockIdx.x & 3;
    const int tid = threadIdx.x;
    const int w = tid >> 6;
    const int lane = tid & 63;
    const int l15 = lane & 15;
    const int quad = lane >> 4;
    const int j = slice * 64 + w * 16 + l15;  // owned hidden column (C-layout col)
    const float bdec = bd[j];

    // B fragments: B[k][n], lane n=l15, k = q*32 + quad*8 + e  -> U4t[mat][n][k]
    short8 Bf[5][8];
#pragma unroll
    for (int g = 0; g < 5; ++g)
#pragma unroll
        for (int q = 0; q < 8; ++q)
            Bf[g][q] = *(const short8*)(U4t + (g << 16) + (j << 8) + (q << 5) + (quad << 3));

    float creg[2][4], hreg[2][4];
#pragma unroll
    for (int mt = 0; mt < 2; ++mt)
#pragma unroll
        for (int r = 0; r < 4; ++r) { creg[mt][r] = 0.f; hreg[mt][r] = 0.f; }

    for (int s = 0; s < SLEN; ++s) {
        const int sf = d ? (SLEN - 1 - s) : s;              // G source row
        const int tt = d ? (s == 0 ? 0 : SLEN - s) : s;     // tb = [t0, t511..t1]

        // ---- prefetch (independent of exchange): G preacts -> acc init, T ----
        float4v acc[5][2];
#pragma unroll
        for (int g = 0; g < 4; ++g)
#pragma unroll
            for (int mt = 0; mt < 2; ++mt) {
                const u16* Gp = G + (size_t)((mt * 16 + quad * 4) * SLEN + sf) * NDIM + g * 256 + j;
                float4v a;
#pragma unroll
                for (int r = 0; r < 4; ++r) a[r] = bf2f(Gp[(size_t)r * SLEN * NDIM]);
                acc[g][mt] = a;
            }
        float Tv[2][4];
#pragma unroll
        for (int mt = 0; mt < 2; ++mt)
#pragma unroll
            for (int r = 0; r < 4; ++r) {
                const int b = mt * 16 + quad * 4 + r;
                Tv[mt][r] = 1.f / logf(times[b * SLEN + tt] + 2.718281828459045f);
            }
#pragma unroll
        for (int mt = 0; mt < 2; ++mt) acc[4][mt] = (float4v)(bdec);

        if (s > 0) {
            // ---- spin until all 32 owned entries carry tag s-1, then stage to LDS ----
            const u64* ex = exch + ((size_t)((d << 1) | ((s - 1) & 1)) << 13);
            u64 vals[32];
            bool ok = false;
            while (!ok) {
                ok = true;
#pragma unroll
                for (int i = 0; i < 32; ++i)
                    vals[i] = __hip_atomic_load(&ex[(i << 8) | tid], __ATOMIC_RELAXED,
                                                __HIP_MEMORY_SCOPE_AGENT);
#pragma unroll
                for (int i = 0; i < 32; ++i)
                    ok = ok && ((u32)vals[i] == (u32)(s - 1));
            }
#pragma unroll
            for (int i = 0; i < 32; ++i) {
                u32 hi = (u32)(vals[i] >> 32);
                hL[i * 264 + tid] = (u16)(hi & 0xffffu);
                cL[i * 264 + tid] = (u16)(hi >> 16);
            }
            __syncthreads();

            // ---- A fragments from LDS: A[m][k], m=l15, k = q*32 + quad*8 + e ----
            short8 Ah[2][8], Ac[2][8];
#pragma unroll
            for (int mt = 0; mt < 2; ++mt)
#pragma unroll
                for (int q = 0; q < 8; ++q) {
                    const int off = (mt * 16 + l15) * 264 + q * 32 + quad * 8;
                    Ah[mt][q] = *(const short8*)(hL + off);
                    Ac[mt][q] = *(const short8*)(cL + off);
                }
#pragma unroll
            for (int q = 0; q < 8; ++q)
#pragma unroll
                for (int mt = 0; mt < 2; ++mt) {
                    acc[0][mt] = __builtin_amdgcn_mfma_f32_16x16x32_bf16(Ah[mt][q], Bf[0][q], acc[0][mt], 0, 0, 0);
                    acc[1][mt] = __builtin_amdgcn_mfma_f32_16x16x32_bf16(Ah[mt][q], Bf[1][q], acc[1][mt], 0, 0, 0);
                    acc[2][mt] = __builtin_amdgcn_mfma_f32_16x16x32_bf16(Ah[mt][q], Bf[2][q], acc[2][mt], 0, 0, 0);
                    acc[3][mt] = __builtin_amdgcn_mfma_f32_16x16x32_bf16(Ah[mt][q], Bf[3][q], acc[3][mt], 0, 0, 0);
                    acc[4][mt] = __builtin_amdgcn_mfma_f32_16x16x32_bf16(Ac[mt][q], Bf[4][q], acc[4][mt], 0, 0, 0);
                }
            __syncthreads();  // LDS free before next step's stage
        }

        // ---- epilogue: C layout col=l15 (j), row=quad*4+r (batch) ----
        u64* exw = exch + ((size_t)((d << 1) | (s & 1)) << 13);
#pragma unroll
        for (int mt = 0; mt < 2; ++mt)
#pragma unroll
            for (int r = 0; r < 4; ++r) {
                const int b = mt * 16 + quad * 4 + r;
                const float C_ST = tanh_f(acc[4][mt][r]);
                const float cs = creg[mt][r] - C_ST + Tv[mt][r] * C_ST;
                const float ig = sigm(acc[0][mt][r]);
                const float fg = sigm(acc[1][mt][r]);
                const float og = sigm(acc[2][mt][r]);
                const float Cc = sigm(acc[3][mt][r]);
                const float cn = fg * cs + ig * Cc;
                const float hn = og * tanh_f(cn);
                creg[mt][r] = cn;
                hreg[mt][r] = hn;
                const u32 payload = ((u32)f2bf(cn) << 16) | (u32)f2bf(hn);
                const u64 v = ((u64)payload << 32) | (u32)s;
                __hip_atomic_store(&exw[(b << 8) | j], v, __ATOMIC_RELAXED,
                                   __HIP_MEMORY_SCOPE_AGENT);
                out[((size_t)b * SLEN + s) * 512 + d * 256 + j] = hn;
            }
    }

    // h_last, c_last
    const size_t base2 = (size_t)BATCH * SLEN * 512;
#pragma unroll
    for (int mt = 0; mt < 2; ++mt)
#pragma unroll
        for (int r = 0; r < 4; ++r) {
            const int b = mt * 16 + quad * 4 + r;
            out[base2 + b * 512 + d * 256 + j] = hreg[mt][r];
            out[base2 + BATCH * 512 + b * 512 + d * 256 + j] = creg[mt][r];
        }
}

extern "C" void kernel_launch(void* const* d_in, const int* in_sizes, int n_in,
                              void* d_out, int out_size, void* d_ws, size_t ws_size,
                              hipStream_t stream) {
    const float* inputs = (const float*)d_in[0];
    const float* times = (const float*)d_in[1];
    WPtrs p;
    p.Wi = (const float*)d_in[2];  p.Ui = (const float*)d_in[3];  p.bi = (const float*)d_in[4];
    p.Wf = (const float*)d_in[5];  p.Uf = (const float*)d_in[6];  p.bfp = (const float*)d_in[7];
    p.Wog = (const float*)d_in[8]; p.Uog = (const float*)d_in[9]; p.bog = (const float*)d_in[10];
    p.Wc = (const float*)d_in[11]; p.Uc = (const float*)d_in[12]; p.bc = (const float*)d_in[13];
    p.Wd = (const float*)d_in[14]; p.bd = (const float*)d_in[15];

    char* ws = (char*)d_ws;
    u16* W4t = (u16*)ws;                   // 1024*768*2   = 1,572,864 B (gemm phase only)
    u16* U4t = (u16*)(ws + 1572864);       // 5*256*256*2  =   655,360 B
    float* b4 = (float*)(ws + 2228224);    // 1024*4       =     4,096 B
    u16* G = (u16*)(ws + 2232320);         // 16384*1024*2 = 33,554,432 B
    // recur-phase exchange aliases the (dead) W4t region:
    u64* exch = (u64*)ws;                  // [2 dir][2 par][32 b][256 k] u64 = 262,144 B

    hipLaunchKernelGGL(convert_kernel, dim3(1024), dim3(256), 0, stream, p, W4t, U4t, b4);
    hipLaunchKernelGGL(gemm_g_kernel, dim3(8, 128), dim3(256), 0, stream, inputs, W4t, b4, G);
    hipMemsetAsync(ws, 0xFF, 262144, stream);  // tags -> 0xFFFFFFFF (never a valid step)
    hipLaunchKernelGGL(recur_mfma_kernel, dim3(8), dim3(256), 0, stream, times, p.bd, U4t, G,
                       exch, (float*)d_out);
}